// Round 1
// 35.156 us; speedup vs baseline: 1.0505x; 1.0505x over previous
//
#include <hip/hip_runtime.h>
#include <hip/hip_bf16.h>

// YOLOv4 head transform, B=16, A=3, nc=80, H=W=76.
// x[b, a*85+ch, h, w] -> out[b, a*H*W + h*W + w, k], k in 0..83.
// R8: R7's structure (loads-first register staging, channel-major LDS with
// odd stride, single barrier, float4-chunk drain) but PT 64->128 with 512
// threads: each channel-row read is now 512 B contiguous (was 256 B),
// halving DRAM page transitions on the scattered 85-row read stream.
// LDS 85*129*4 = 43,860 B -> 3 blocks/CU -> 24 waves/CU.

#define YHW 5776
#define PT 128
#define NT 46              // 45 full 128-pos tiles + one 16-pos tail per plane
#define LSTRIDE 129        // odd stride: drain reads stay ~2-way (free-ish)
#define NTHREADS 512

typedef float f4v __attribute__((ext_vector_type(4)));

__device__ __forceinline__ float fsigmoid(float v) {
    return __builtin_amdgcn_rcpf(1.0f + __expf(-v));
}

// QL = log2(float4s per channel row): 5 (npos=128) or 2 (npos=16)
template<int QL>
__device__ __forceinline__ void build(const float* __restrict__ src,
                                      float (*lds)[LSTRIDE], int tid) {
    constexpr int NQ = 85 << QL;                    // 2720 / 340
    constexpr int NJ = (NQ + NTHREADS - 1) / NTHREADS;  // 6 / 1
    f4v r[NJ];
    #pragma unroll
    for (int j = 0; j < NJ; ++j) {                  // ALL loads issued before any use
        const int idx = tid + NTHREADS * j;
        if (idx < NQ) {
            const int ch = idx >> QL;
            const int q  = idx & ((1 << QL) - 1);
            r[j] = *reinterpret_cast<const f4v*>(src + (size_t)ch * YHW + 4 * q);
        }
    }
    #pragma unroll
    for (int j = 0; j < NJ; ++j) {
        const int idx = tid + NTHREADS * j;
        if (idx < NQ) {
            const int ch = idx >> QL;
            const int q  = idx & ((1 << QL) - 1);
            f4v v = r[j];
            int row;
            if (ch < 2) {                   // tx,ty -> sigmoid*1.2-0.1
                v.x = fsigmoid(v.x) * 1.2f - 0.1f;
                v.y = fsigmoid(v.y) * 1.2f - 0.1f;
                v.z = fsigmoid(v.z) * 1.2f - 0.1f;
                v.w = fsigmoid(v.w) * 1.2f - 0.1f;
                row = ch;
            } else if (ch < 4) {            // tw,th -> exp
                v.x = __expf(v.x); v.y = __expf(v.y);
                v.z = __expf(v.z); v.w = __expf(v.w);
                row = ch;
            } else {                        // det + classes -> sigmoid
                v.x = fsigmoid(v.x); v.y = fsigmoid(v.y);
                v.z = fsigmoid(v.z); v.w = fsigmoid(v.w);
                row = (ch == 4) ? 84 : ch - 1;   // class ch -> row k (4..83)
            }
            const int p4 = 4 * q;
            lds[row][p4 + 0] = v.x;
            lds[row][p4 + 1] = v.y;
            lds[row][p4 + 2] = v.z;
            lds[row][p4 + 3] = v.w;
        }
    }
}

__global__ __launch_bounds__(NTHREADS) void yolo_kernel(const float* __restrict__ x,
                                                        float* __restrict__ out) {
    const int blk  = blockIdx.x;
    const int tile = blk % NT;
    const int ba   = blk / NT;              // b*3 + a
    const int a    = ba % 3;
    const int p0   = tile * PT;
    const int npos = (tile == NT - 1) ? 16 : PT;

    __shared__ float lds[85][LSTRIDE];      // 43,860 B -> 3 blocks/CU

    const float* __restrict__ src = x + (size_t)ba * 85 * YHW + p0;
    const int tid = threadIdx.x;

    if (npos == PT) build<5>(src, lds, tid);
    else            build<2>(src, lds, tid);
    __syncthreads();                        // the only barrier

    const float ax  = (a == 0) ? 1.5f : ((a == 1) ? 2.375f : 5.0f);
    const float ay  = (a == 0) ? 2.0f : ((a == 1) ? 4.5f : 3.5f);
    const float inv = 1.0f / 76.0f;
    float* __restrict__ dst = out + ((size_t)ba * YHW + p0) * 84;

    const int total = npos * 21;            // 2688 / 336
    for (int u = tid; u < total; u += NTHREADS) {
        const int pp = u / 21;
        const int c  = u - 21 * pp;
        f4v o;
        if (c == 0) {                       // box: rows 0..3, pure arithmetic
            const float sx = lds[0][pp];
            const float sy = lds[1][pp];
            const float ew = lds[2][pp];
            const float eh = lds[3][pp];
            const int p = p0 + pp;
            const int h = p / 76;
            const int w = p - 76 * h;
            const float bxc = (sx + (float)w) * inv;
            const float byc = (sy + (float)h) * inv;
            const float bw  = ew * ax * inv;
            const float bh  = eh * ay * inv;
            const float bx1 = bxc - 0.5f * bw;
            const float by1 = byc - 0.5f * bh;
            o.x = bx1; o.y = by1; o.z = bx1 + bw; o.w = by1 + bh;
        } else {                            // classes k=4c..4c+3 at rows 4c..4c+3
            const float det = lds[84][pp];
            o.x = lds[4 * c + 0][pp] * det;
            o.y = lds[4 * c + 1][pp] * det;
            o.z = lds[4 * c + 2][pp] * det;
            o.w = lds[4 * c + 3][pp] * det;
        }
        *reinterpret_cast<f4v*>(dst + (size_t)pp * 84 + 4 * c) = o;
    }
}

extern "C" void kernel_launch(void* const* d_in, const int* in_sizes, int n_in,
                              void* d_out, int out_size, void* d_ws, size_t ws_size,
                              hipStream_t stream) {
    const float* x = (const float*)d_in[0];
    float* out = (float*)d_out;
    const int nblocks = 48 * NT;            // 16*3*46 = 2208
    yolo_kernel<<<nblocks, NTHREADS, 0, stream>>>(x, out);
}